// Round 2
// baseline (549.621 us; speedup 1.0000x reference)
//
#include <hip/hip_runtime.h>

#define FDIM   128
#define HEADS  4
#define ALPHA  0.2f
#define CN     16            // edge chunk per node iteration

#define SCAN_CHUNK   1024
#define SCAN_THREADS 256

// ---------------- per-node, per-head scores: one wave per node ----------------
__global__ __launch_bounds__(256) void score_kernel(
    const float* __restrict__ x, const float* __restrict__ W,
    const float* __restrict__ a, float* __restrict__ s_src,
    float* __restrict__ s_dst, int n) {
  int lane = threadIdx.x & 63;
  int node = (blockIdx.x << 2) + (threadIdx.x >> 6);
  if (node >= n) return;
  const float2* x2 = (const float2*)x;
  const float2* W2 = (const float2*)W;
  const float2* a2 = (const float2*)a;
  float2 xv = x2[(size_t)node * 64 + lane];
#pragma unroll
  for (int k = 0; k < HEADS; k++) {
    float2 wv = W2[k * 64 + lane];
    float hx = xv.x * wv.x, hy = xv.y * wv.y;
    float2 as_ = a2[k * 128 + lane];        // a[k, 0:F]
    float2 ad_ = a2[k * 128 + 64 + lane];   // a[k, F:2F]
    float rs = hx * as_.x + hy * as_.y;
    float rd = hx * ad_.x + hy * ad_.y;
#pragma unroll
    for (int off = 32; off > 0; off >>= 1) {
      rs += __shfl_down(rs, off);
      rd += __shfl_down(rd, off);
    }
    if (lane == 0) {
      s_src[node * HEADS + k] = rs;
      s_dst[node * HEADS + k] = rd;
    }
  }
}

// ---------------- counting sort: histogram (int4 reads) ----------------
__global__ __launch_bounds__(256) void hist_kernel(const int* __restrict__ src,
                                                   int* __restrict__ counts, int E) {
  int i = blockIdx.x * 256 + threadIdx.x;
  int nq = E >> 2;
  if (i < nq) {
    int4 v = ((const int4*)src)[i];
    atomicAdd(&counts[v.x], 1);
    atomicAdd(&counts[v.y], 1);
    atomicAdd(&counts[v.z], 1);
    atomicAdd(&counts[v.w], 1);
  }
  if (i < (E & 3)) atomicAdd(&counts[src[(nq << 2) + i]], 1);
}

// ---------------- scan step 1: per-chunk sums ----------------
__global__ __launch_bounds__(SCAN_THREADS) void scan1_kernel(const int* __restrict__ counts,
                                                             int* __restrict__ partials, int n) {
  __shared__ int lds[SCAN_THREADS];
  int b = blockIdx.x, t = threadIdx.x;
  int base = b * SCAN_CHUNK + t * 4;
  int s = 0;
#pragma unroll
  for (int j = 0; j < 4; j++) {
    int i = base + j;
    s += (i < n) ? counts[i] : 0;
  }
  lds[t] = s;
  __syncthreads();
  for (int off = SCAN_THREADS / 2; off > 0; off >>= 1) {
    if (t < off) lds[t] += lds[t + off];
    __syncthreads();
  }
  if (t == 0) partials[b] = lds[0];
}

// ---------------- scan step 2+3 fused: row_ptr + cursor ----------------
// Each block reduces partials[0..b-1] itself (P <= SCAN_THREADS), no scan2.
__global__ __launch_bounds__(SCAN_THREADS) void scan3_kernel(
    const int* __restrict__ counts, const int* __restrict__ partials,
    int* __restrict__ row_ptr, int* __restrict__ cursor, int n, int P, int Etot) {
  __shared__ int sred[SCAN_THREADS];
  __shared__ int lds[SCAN_THREADS];
  int b = blockIdx.x, t = threadIdx.x;

  // prefix of chunk sums for this block
  sred[t] = (t < P && t < b) ? partials[t] : 0;
  __syncthreads();
  for (int off = SCAN_THREADS / 2; off > 0; off >>= 1) {
    if (t < off) sred[t] += sred[t + off];
    __syncthreads();
  }
  int pref = sred[0];
  __syncthreads();

  int base = b * SCAN_CHUNK + t * 4;
  int v[4];
  int s = 0;
#pragma unroll
  for (int j = 0; j < 4; j++) {
    int i = base + j;
    v[j] = (i < n) ? counts[i] : 0;
    s += v[j];
  }
  int mine = s;
  lds[t] = s;
  __syncthreads();
  for (int off = 1; off < SCAN_THREADS; off <<= 1) {
    int xv = (t >= off) ? lds[t - off] : 0;
    __syncthreads();
    lds[t] += xv;
    __syncthreads();
  }
  int run = pref + (lds[t] - mine);
#pragma unroll
  for (int j = 0; j < 4; j++) {
    int i = base + j;
    if (i < n) {
      row_ptr[i] = run;
      cursor[i]  = run;
    }
    run += v[j];
  }
  if (b == 0 && t == 0) row_ptr[n] = Etot;
}

// ---------------- counting sort: scatter (packed 8B payload) ----------------
__global__ __launch_bounds__(256) void scatter_kernel(
    const int* __restrict__ src, const int* __restrict__ dst,
    const float* __restrict__ adj, int* __restrict__ cursor,
    int2* __restrict__ edge_sorted, int E) {
  int i = blockIdx.x * 256 + threadIdx.x;
  if (i >= E) return;
  int s = src[i];
  int pos = atomicAdd(&cursor[s], 1);
  int2 pk;
  pk.x = dst[i];
  pk.y = __float_as_int(adj[i]);
  edge_sorted[pos] = pk;
}

// ---------------- main aggregation: one WAVE per node, float2/thread ----------------
__global__ __launch_bounds__(256) void aggregate_kernel(
    const float* __restrict__ x, const float* __restrict__ W,
    const float* __restrict__ s_src, const float* __restrict__ s_dst,
    const int* __restrict__ row_ptr, const int2* __restrict__ edge_sorted,
    float* __restrict__ out, int n) {
  int wid  = threadIdx.x >> 6;          // wave (node slot) within block: 0..3
  int lane = threadIdx.x & 63;
  int node = blockIdx.x * 4 + wid;
  bool active = node < n;
  int beg = active ? row_ptr[node]     : 0;
  int end = active ? row_ptr[node + 1] : 0;

  __shared__ float se[4][CN * HEADS];   // [wave][edge*4 + head]
  __shared__ int   sd[4][CN];           // [wave][edge] dst ids
  __shared__ float sfin[4][HEADS];      // rowsums

  int e = lane >> 2;                    // edge slot 0..15
  int k = lane & 3;                     // head
  float ssrc_k = active ? s_src[node * HEADS + k] : 0.f;
  float rsum = 0.f;                     // rowsum for head k (redundant per lane)

  float2 acc[HEADS] = {{0.f,0.f},{0.f,0.f},{0.f,0.f},{0.f,0.f}};
  const float2* x2 = (const float2*)x;

  for (int c = beg; c < end; c += CN) {
    int cn = end - c; if (cn > CN) cn = CN;
    // cooperative e-value computation: lane (e,k) handles edge e, head k
    float ev = 0.f;
    if (e < cn) {
      int2 ed = edge_sorted[c + e];
      if (k == 0) sd[wid][e] = ed.x;
      float s = ssrc_k + s_dst[ed.x * HEADS + k];
      s = (s >= 0.f) ? s : ALPHA * s;
      ev = __expf(s) * __int_as_float(ed.y);
    }
    se[wid][lane] = ev;
    // rowsum over edges (same k): butterfly on xor 4,8,16,32
    float r = ev;
    r += __shfl_xor(r, 4);
    r += __shfl_xor(r, 8);
    r += __shfl_xor(r, 16);
    r += __shfl_xor(r, 32);
    rsum += r;
    __syncthreads();
    for (int e2 = 0; e2 < cn; e2++) {
      int d = sd[wid][e2];
      float2 xv = x2[(size_t)d * 64 + lane];
      float4 s4 = *(const float4*)&se[wid][e2 * 4];
      acc[0].x += s4.x * xv.x; acc[0].y += s4.x * xv.y;
      acc[1].x += s4.y * xv.x; acc[1].y += s4.y * xv.y;
      acc[2].x += s4.z * xv.x; acc[2].y += s4.z * xv.y;
      acc[3].x += s4.w * xv.x; acc[3].y += s4.w * xv.y;
    }
    __syncthreads();
  }

  if (lane < HEADS) sfin[wid][lane] = rsum;   // lanes 0..3 hold k=0..3
  __syncthreads();

  if (active) {
    const float2* W2 = (const float2*)W;
    float2 o = {0.f, 0.f};
#pragma unroll
    for (int kk = 0; kk < HEADS; kk++) {
      float2 wv = W2[kk * 64 + lane];
      float inv = 1.0f / sfin[wid][kk];
      float hx = wv.x * acc[kk].x * inv;
      float hy = wv.y * acc[kk].y * inv;
      o.x += (hx > 0.f) ? hx : expm1f(hx);
      o.y += (hy > 0.f) ? hy : expm1f(hy);
    }
    float2* out2 = (float2*)out;
    o.x *= 0.25f; o.y *= 0.25f;
    out2[(size_t)node * 64 + lane] = o;
  }
}

extern "C" void kernel_launch(void* const* d_in, const int* in_sizes, int n_in,
                              void* d_out, int out_size, void* d_ws, size_t ws_size,
                              hipStream_t stream) {
  const float* x   = (const float*)d_in[0];
  const int*   edg = (const int*)d_in[1];
  const float* adj = (const float*)d_in[2];
  const float* W   = (const float*)d_in[3];
  const float* a   = (const float*)d_in[4];
  float* out = (float*)d_out;

  int E = in_sizes[2];
  int n = in_sizes[0] / FDIM;
  const int* src = edg;
  const int* dst = edg + E;

  auto align = [](size_t v) { return (v + 255) & ~(size_t)255; };
  char* ws = (char*)d_ws;
  int*   counts      = (int*)ws;   ws += align((size_t)n * 4);
  int*   row_ptr     = (int*)ws;   ws += align((size_t)(n + 1) * 4);
  int*   cursor      = (int*)ws;   ws += align((size_t)n * 4);
  int*   partials    = (int*)ws;   ws += align(SCAN_THREADS * 4);
  int2*  edge_sorted = (int2*)ws;  ws += align((size_t)E * 8);
  float* s_src       = (float*)ws; ws += align((size_t)n * HEADS * 4);
  float* s_dst       = (float*)ws; ws += align((size_t)n * HEADS * 4);

  int P = (n + SCAN_CHUNK - 1) / SCAN_CHUNK;   // <= SCAN_THREADS for n <= 262144

  hipMemsetAsync(counts, 0, (size_t)n * 4, stream);

  score_kernel<<<(n + 3) / 4, 256, 0, stream>>>(x, W, a, s_src, s_dst, n);
  hist_kernel<<<((E >> 2) + 255) / 256, 256, 0, stream>>>(src, counts, E);
  scan1_kernel<<<P, SCAN_THREADS, 0, stream>>>(counts, partials, n);
  scan3_kernel<<<P, SCAN_THREADS, 0, stream>>>(counts, partials, row_ptr, cursor, n, P, E);
  scatter_kernel<<<(E + 255) / 256, 256, 0, stream>>>(src, dst, adj, cursor, edge_sorted, E);
  aggregate_kernel<<<(n + 3) / 4, 256, 0, stream>>>(x, W, s_src, s_dst, row_ptr,
                                                    edge_sorted, out, n);
}

// Round 3
// 465.576 us; speedup vs baseline: 1.1805x; 1.1805x over previous
//
#include <hip/hip_runtime.h>

#define FDIM   128
#define HEADS  4
#define ALPHA  0.2f
#define CN     16            // edge chunk per wave iteration

#define SCAN_CHUNK   1024
#define SCAN_THREADS 256

__device__ __forceinline__ float readlane_f(float v, int lane) {
  return __int_as_float(__builtin_amdgcn_readlane(__float_as_int(v), lane));
}

// ---------------- per-node, per-head scores: one wave per node ----------------
// also zeroes counts[] (saves a memset dispatch; stream order guarantees it
// completes before hist_kernel)
__global__ __launch_bounds__(256) void score_kernel(
    const float* __restrict__ x, const float* __restrict__ W,
    const float* __restrict__ a, float* __restrict__ s_src,
    float* __restrict__ s_dst, int* __restrict__ counts, int n) {
  int lane = threadIdx.x & 63;
  int node = (blockIdx.x << 2) + (threadIdx.x >> 6);
  if (node >= n) return;
  if (lane == 0) counts[node] = 0;
  const float2* x2 = (const float2*)x;
  const float2* W2 = (const float2*)W;
  const float2* a2 = (const float2*)a;
  float2 xv = x2[(size_t)node * 64 + lane];
#pragma unroll
  for (int k = 0; k < HEADS; k++) {
    float2 wv = W2[k * 64 + lane];
    float hx = xv.x * wv.x, hy = xv.y * wv.y;
    float2 as_ = a2[k * 128 + lane];        // a[k, 0:F]
    float2 ad_ = a2[k * 128 + 64 + lane];   // a[k, F:2F]
    float rs = hx * as_.x + hy * as_.y;
    float rd = hx * ad_.x + hy * ad_.y;
#pragma unroll
    for (int off = 32; off > 0; off >>= 1) {
      rs += __shfl_down(rs, off);
      rd += __shfl_down(rd, off);
    }
    if (lane == 0) {
      s_src[node * HEADS + k] = rs;
      s_dst[node * HEADS + k] = rd;
    }
  }
}

// ---------------- counting sort: histogram (int4 reads) ----------------
__global__ __launch_bounds__(256) void hist_kernel(const int* __restrict__ src,
                                                   int* __restrict__ counts, int E) {
  int i = blockIdx.x * 256 + threadIdx.x;
  int nq = E >> 2;
  if (i < nq) {
    int4 v = ((const int4*)src)[i];
    atomicAdd(&counts[v.x], 1);
    atomicAdd(&counts[v.y], 1);
    atomicAdd(&counts[v.z], 1);
    atomicAdd(&counts[v.w], 1);
  }
  if (i < (E & 3)) atomicAdd(&counts[src[(nq << 2) + i]], 1);
}

// ---------------- scan step 1: per-chunk sums ----------------
__global__ __launch_bounds__(SCAN_THREADS) void scan1_kernel(const int* __restrict__ counts,
                                                             int* __restrict__ partials, int n) {
  __shared__ int lds[SCAN_THREADS];
  int b = blockIdx.x, t = threadIdx.x;
  int base = b * SCAN_CHUNK + t * 4;
  int s = 0;
#pragma unroll
  for (int j = 0; j < 4; j++) {
    int i = base + j;
    s += (i < n) ? counts[i] : 0;
  }
  lds[t] = s;
  __syncthreads();
  for (int off = SCAN_THREADS / 2; off > 0; off >>= 1) {
    if (t < off) lds[t] += lds[t + off];
    __syncthreads();
  }
  if (t == 0) partials[b] = lds[0];
}

// ---------------- scan step 2+3 fused: row_ptr + cursor ----------------
__global__ __launch_bounds__(SCAN_THREADS) void scan3_kernel(
    const int* __restrict__ counts, const int* __restrict__ partials,
    int* __restrict__ row_ptr, int* __restrict__ cursor, int n, int P, int Etot) {
  __shared__ int sred[SCAN_THREADS];
  __shared__ int lds[SCAN_THREADS];
  int b = blockIdx.x, t = threadIdx.x;

  sred[t] = (t < P && t < b) ? partials[t] : 0;
  __syncthreads();
  for (int off = SCAN_THREADS / 2; off > 0; off >>= 1) {
    if (t < off) sred[t] += sred[t + off];
    __syncthreads();
  }
  int pref = sred[0];
  __syncthreads();

  int base = b * SCAN_CHUNK + t * 4;
  int v[4];
  int s = 0;
#pragma unroll
  for (int j = 0; j < 4; j++) {
    int i = base + j;
    v[j] = (i < n) ? counts[i] : 0;
    s += v[j];
  }
  int mine = s;
  lds[t] = s;
  __syncthreads();
  for (int off = 1; off < SCAN_THREADS; off <<= 1) {
    int xv = (t >= off) ? lds[t - off] : 0;
    __syncthreads();
    lds[t] += xv;
    __syncthreads();
  }
  int run = pref + (lds[t] - mine);
#pragma unroll
  for (int j = 0; j < 4; j++) {
    int i = base + j;
    if (i < n) {
      row_ptr[i] = run;
      cursor[i]  = run;
    }
    run += v[j];
  }
  if (b == 0 && t == 0) row_ptr[n] = Etot;
}

// ---------------- counting sort: scatter (packed 8B payload) ----------------
__global__ __launch_bounds__(256) void scatter_kernel(
    const int* __restrict__ src, const int* __restrict__ dst,
    const float* __restrict__ adj, int* __restrict__ cursor,
    int2* __restrict__ edge_sorted, int E) {
  int i = blockIdx.x * 256 + threadIdx.x;
  if (i >= E) return;
  int s = src[i];
  int pos = atomicAdd(&cursor[s], 1);
  int2 pk;
  pk.x = dst[i];
  pk.y = __float_as_int(adj[i]);
  edge_sorted[pos] = pk;
}

// ---------------- main aggregation: one WAVE per node, no LDS, no barriers ---
__global__ __launch_bounds__(256, 8) void aggregate_kernel(
    const float* __restrict__ x, const float* __restrict__ W,
    const float* __restrict__ s_src, const float* __restrict__ s_dst,
    const int* __restrict__ row_ptr, const int2* __restrict__ edge_sorted,
    float* __restrict__ out, int n) {
  int lane = threadIdx.x & 63;
  int node = (blockIdx.x << 2) + (threadIdx.x >> 6);
  if (node >= n) return;                 // wave-uniform; no barriers anywhere
  int beg = row_ptr[node], end = row_ptr[node + 1];
  int e = lane >> 2;                     // edge slot 0..15
  int k = lane & 3;                      // head
  float ssrc_k = s_src[node * HEADS + k];
  const float2* x2 = (const float2*)x;

  float2 acc0{0.f,0.f}, acc1{0.f,0.f}, acc2{0.f,0.f}, acc3{0.f,0.f};
  float rsum = 0.f;

  // broadcast-and-accumulate one edge; d/s0..s3 land in SGPRs (readlane)
  auto body = [&](int dxv, float evv, int e2) {
    int   d  = __builtin_amdgcn_readlane(dxv, e2 * 4);
    float s0 = readlane_f(evv, e2 * 4 + 0);
    float s1 = readlane_f(evv, e2 * 4 + 1);
    float s2 = readlane_f(evv, e2 * 4 + 2);
    float s3 = readlane_f(evv, e2 * 4 + 3);
    float2 xv = x2[(size_t)d * 64 + lane];
    acc0.x += s0 * xv.x; acc0.y += s0 * xv.y;
    acc1.x += s1 * xv.x; acc1.y += s1 * xv.y;
    acc2.x += s2 * xv.x; acc2.y += s2 * xv.y;
    acc3.x += s3 * xv.x; acc3.y += s3 * xv.y;
  };

  int c = beg;
  for (; c + CN <= end; c += CN) {       // full chunks, fixed trip count
    int2 ed = edge_sorted[c + e];
    float s = ssrc_k + s_dst[ed.x * HEADS + k];
    s = (s >= 0.f) ? s : ALPHA * s;
    float ev = __expf(s) * __int_as_float(ed.y);
    rsum += ev;
#pragma unroll 4
    for (int e2 = 0; e2 < CN; e2++) body(ed.x, ev, e2);
  }
  int cn = end - c;                      // tail: 0..15 edges
  if (cn > 0) {
    int dx = 0; float ev = 0.f;
    if (e < cn) {
      int2 ed = edge_sorted[c + e];
      dx = ed.x;
      float s = ssrc_k + s_dst[dx * HEADS + k];
      s = (s >= 0.f) ? s : ALPHA * s;
      ev = __expf(s) * __int_as_float(ed.y);
    }
    rsum += ev;
    for (int e2 = 0; e2 < cn; e2++) body(dx, ev, e2);
  }

  // rowsum per head: butterfly over lanes with equal (lane&3)
  rsum += __shfl_xor(rsum, 4);
  rsum += __shfl_xor(rsum, 8);
  rsum += __shfl_xor(rsum, 16);
  rsum += __shfl_xor(rsum, 32);
  float r0 = readlane_f(rsum, 0), r1 = readlane_f(rsum, 1);
  float r2 = readlane_f(rsum, 2), r3 = readlane_f(rsum, 3);

  const float2* W2 = (const float2*)W;
  float2 o{0.f, 0.f};
  {
    float2 wv = W2[0 * 64 + lane];
    float hx = wv.x * acc0.x / r0, hy = wv.y * acc0.y / r0;
    o.x += (hx > 0.f) ? hx : expm1f(hx); o.y += (hy > 0.f) ? hy : expm1f(hy);
  }
  {
    float2 wv = W2[1 * 64 + lane];
    float hx = wv.x * acc1.x / r1, hy = wv.y * acc1.y / r1;
    o.x += (hx > 0.f) ? hx : expm1f(hx); o.y += (hy > 0.f) ? hy : expm1f(hy);
  }
  {
    float2 wv = W2[2 * 64 + lane];
    float hx = wv.x * acc2.x / r2, hy = wv.y * acc2.y / r2;
    o.x += (hx > 0.f) ? hx : expm1f(hx); o.y += (hy > 0.f) ? hy : expm1f(hy);
  }
  {
    float2 wv = W2[3 * 64 + lane];
    float hx = wv.x * acc3.x / r3, hy = wv.y * acc3.y / r3;
    o.x += (hx > 0.f) ? hx : expm1f(hx); o.y += (hy > 0.f) ? hy : expm1f(hy);
  }
  o.x *= 0.25f; o.y *= 0.25f;
  ((float2*)out)[(size_t)node * 64 + lane] = o;
}

extern "C" void kernel_launch(void* const* d_in, const int* in_sizes, int n_in,
                              void* d_out, int out_size, void* d_ws, size_t ws_size,
                              hipStream_t stream) {
  const float* x   = (const float*)d_in[0];
  const int*   edg = (const int*)d_in[1];
  const float* adj = (const float*)d_in[2];
  const float* W   = (const float*)d_in[3];
  const float* a   = (const float*)d_in[4];
  float* out = (float*)d_out;

  int E = in_sizes[2];
  int n = in_sizes[0] / FDIM;
  const int* src = edg;
  const int* dst = edg + E;

  auto align = [](size_t v) { return (v + 255) & ~(size_t)255; };
  char* ws = (char*)d_ws;
  int*   counts      = (int*)ws;   ws += align((size_t)n * 4);
  int*   row_ptr     = (int*)ws;   ws += align((size_t)(n + 1) * 4);
  int*   cursor      = (int*)ws;   ws += align((size_t)n * 4);
  int*   partials    = (int*)ws;   ws += align(SCAN_THREADS * 4);
  int2*  edge_sorted = (int2*)ws;  ws += align((size_t)E * 8);
  float* s_src       = (float*)ws; ws += align((size_t)n * HEADS * 4);
  float* s_dst       = (float*)ws; ws += align((size_t)n * HEADS * 4);

  int P = (n + SCAN_CHUNK - 1) / SCAN_CHUNK;   // <= SCAN_THREADS

  score_kernel<<<(n + 3) / 4, 256, 0, stream>>>(x, W, a, s_src, s_dst, counts, n);
  hist_kernel<<<((E >> 2) + 255) / 256, 256, 0, stream>>>(src, counts, E);
  scan1_kernel<<<P, SCAN_THREADS, 0, stream>>>(counts, partials, n);
  scan3_kernel<<<P, SCAN_THREADS, 0, stream>>>(counts, partials, row_ptr, cursor, n, P, E);
  scatter_kernel<<<(E + 255) / 256, 256, 0, stream>>>(src, dst, adj, cursor, edge_sorted, E);
  aggregate_kernel<<<(n + 3) / 4, 256, 0, stream>>>(x, W, s_src, s_dst, row_ptr,
                                                    edge_sorted, out, n);
}

// Round 4
// 459.455 us; speedup vs baseline: 1.1962x; 1.0133x over previous
//
#include <hip/hip_runtime.h>

#define FDIM   128
#define HEADS  4
#define ALPHA  0.2f
#define CN     16            // edge chunk per wave iteration

#define SCAN_CHUNK   1024
#define SCAN_THREADS 256

__device__ __forceinline__ float readlane_f(float v, int lane) {
  return __int_as_float(__builtin_amdgcn_readlane(__float_as_int(v), lane));
}

// ---------------- per-node, per-head scores: one wave per node ----------------
// also zeroes counts[] (stream order guarantees completion before hist_kernel)
__global__ __launch_bounds__(256) void score_kernel(
    const float* __restrict__ x, const float* __restrict__ W,
    const float* __restrict__ a, float* __restrict__ s_src,
    float* __restrict__ s_dst, int* __restrict__ counts, int n) {
  int lane = threadIdx.x & 63;
  int node = (blockIdx.x << 2) + (threadIdx.x >> 6);
  if (node >= n) return;
  if (lane == 0) counts[node] = 0;
  const float2* x2 = (const float2*)x;
  const float2* W2 = (const float2*)W;
  const float2* a2 = (const float2*)a;
  float2 xv = x2[(size_t)node * 64 + lane];
#pragma unroll
  for (int k = 0; k < HEADS; k++) {
    float2 wv = W2[k * 64 + lane];
    float hx = xv.x * wv.x, hy = xv.y * wv.y;
    float2 as_ = a2[k * 128 + lane];        // a[k, 0:F]
    float2 ad_ = a2[k * 128 + 64 + lane];   // a[k, F:2F]
    float rs = hx * as_.x + hy * as_.y;
    float rd = hx * ad_.x + hy * ad_.y;
#pragma unroll
    for (int off = 32; off > 0; off >>= 1) {
      rs += __shfl_down(rs, off);
      rd += __shfl_down(rd, off);
    }
    if (lane == 0) {
      s_src[node * HEADS + k] = rs;
      s_dst[node * HEADS + k] = rd;
    }
  }
}

// ---------------- counting sort: histogram (int4 reads) ----------------
__global__ __launch_bounds__(256) void hist_kernel(const int* __restrict__ src,
                                                   int* __restrict__ counts, int E) {
  int i = blockIdx.x * 256 + threadIdx.x;
  int nq = E >> 2;
  if (i < nq) {
    int4 v = ((const int4*)src)[i];
    atomicAdd(&counts[v.x], 1);
    atomicAdd(&counts[v.y], 1);
    atomicAdd(&counts[v.z], 1);
    atomicAdd(&counts[v.w], 1);
  }
  if (i < (E & 3)) atomicAdd(&counts[src[(nq << 2) + i]], 1);
}

// ---------------- scan step 1: per-chunk sums ----------------
__global__ __launch_bounds__(SCAN_THREADS) void scan1_kernel(const int* __restrict__ counts,
                                                             int* __restrict__ partials, int n) {
  __shared__ int lds[SCAN_THREADS];
  int b = blockIdx.x, t = threadIdx.x;
  int base = b * SCAN_CHUNK + t * 4;
  int s = 0;
#pragma unroll
  for (int j = 0; j < 4; j++) {
    int i = base + j;
    s += (i < n) ? counts[i] : 0;
  }
  lds[t] = s;
  __syncthreads();
  for (int off = SCAN_THREADS / 2; off > 0; off >>= 1) {
    if (t < off) lds[t] += lds[t + off];
    __syncthreads();
  }
  if (t == 0) partials[b] = lds[0];
}

// ---------------- scan step 2+3 fused: row_ptr + cursor ----------------
__global__ __launch_bounds__(SCAN_THREADS) void scan3_kernel(
    const int* __restrict__ counts, const int* __restrict__ partials,
    int* __restrict__ row_ptr, int* __restrict__ cursor, int n, int P, int Etot) {
  __shared__ int sred[SCAN_THREADS];
  __shared__ int lds[SCAN_THREADS];
  int b = blockIdx.x, t = threadIdx.x;

  sred[t] = (t < P && t < b) ? partials[t] : 0;
  __syncthreads();
  for (int off = SCAN_THREADS / 2; off > 0; off >>= 1) {
    if (t < off) sred[t] += sred[t + off];
    __syncthreads();
  }
  int pref = sred[0];
  __syncthreads();

  int base = b * SCAN_CHUNK + t * 4;
  int v[4];
  int s = 0;
#pragma unroll
  for (int j = 0; j < 4; j++) {
    int i = base + j;
    v[j] = (i < n) ? counts[i] : 0;
    s += v[j];
  }
  int mine = s;
  lds[t] = s;
  __syncthreads();
  for (int off = 1; off < SCAN_THREADS; off <<= 1) {
    int xv = (t >= off) ? lds[t - off] : 0;
    __syncthreads();
    lds[t] += xv;
    __syncthreads();
  }
  int run = pref + (lds[t] - mine);
#pragma unroll
  for (int j = 0; j < 4; j++) {
    int i = base + j;
    if (i < n) {
      row_ptr[i] = run;
      cursor[i]  = run;
    }
    run += v[j];
  }
  if (b == 0 && t == 0) row_ptr[n] = Etot;
}

// ---------------- counting sort: scatter (packed 8B payload) ----------------
__global__ __launch_bounds__(256) void scatter_kernel(
    const int* __restrict__ src, const int* __restrict__ dst,
    const float* __restrict__ adj, int* __restrict__ cursor,
    int2* __restrict__ edge_sorted, int E) {
  int i = blockIdx.x * 256 + threadIdx.x;
  if (i >= E) return;
  int s = src[i];
  int pos = atomicAdd(&cursor[s], 1);
  int2 pk;
  pk.x = dst[i];
  pk.y = __float_as_int(adj[i]);
  edge_sorted[pos] = pk;
}

// ---------------- main aggregation: one WAVE per node, 8-deep gather MLP -----
// Padding invariant: inactive edge slots carry ed={0,0} -> ev = exp(s)*0 = 0,
// dst = 0 -> the padded fmacs add exactly 0 using a (cached) load of row 0.
__global__ __launch_bounds__(256, 8) void aggregate_kernel(
    const float* __restrict__ x, const float* __restrict__ W,
    const float* __restrict__ s_src, const float* __restrict__ s_dst,
    const int* __restrict__ row_ptr, const int2* __restrict__ edge_sorted,
    float* __restrict__ out, int n) {
  int lane = threadIdx.x & 63;
  int node = (blockIdx.x << 2) + (threadIdx.x >> 6);
  if (node >= n) return;                 // wave-uniform; no barriers anywhere
  int beg = row_ptr[node], end = row_ptr[node + 1];
  int e = lane >> 2;                     // edge slot 0..15
  int k = lane & 3;                      // head
  float ssrc_k = s_src[node * HEADS + k];
  const float2* x2 = (const float2*)x;

  float2 acc0{0.f,0.f}, acc1{0.f,0.f}, acc2{0.f,0.f}, acc3{0.f,0.f};
  float rsum = 0.f;

  // software-pipelined chunk loop: next chunk's edge payload loads during
  // the current chunk's gather+fmac phase
  int c = beg;
  int cn = end - c; if (cn > CN) cn = CN;
  int2 ed{0, 0};
  if (e < cn) ed = edge_sorted[c + e];

  while (c < end) {
    // e-value for this lane's (edge, head); padded lanes give exactly 0
    float s = ssrc_k + s_dst[ed.x * HEADS + k];
    s = (s >= 0.f) ? s : ALPHA * s;
    float ev = __expf(s) * __int_as_float(ed.y);
    rsum += ev;

    // prefetch next chunk's payload
    int cnx = c + CN;
    int cn2 = end - cnx; if (cn2 > CN) cn2 = CN;
    int2 ed2{0, 0};
    if (cnx < end && e < cn2) ed2 = edge_sorted[cnx + e];

    // groups of 8 edges: 8 independent row-gathers in flight
    int gmax = (cn + 7) & ~7;            // 8 or 16
    for (int g = 0; g < gmax; g += 8) {
      int dd[8];
      float2 xv[8];
#pragma unroll
      for (int j = 0; j < 8; j++)
        dd[j] = __builtin_amdgcn_readlane(ed.x, (g + j) * 4);
#pragma unroll
      for (int j = 0; j < 8; j++)
        xv[j] = x2[(size_t)dd[j] * 64 + lane];
#pragma unroll
      for (int j = 0; j < 8; j++) {
        int b = (g + j) * 4;
        float s0 = readlane_f(ev, b + 0);
        float s1 = readlane_f(ev, b + 1);
        float s2 = readlane_f(ev, b + 2);
        float s3 = readlane_f(ev, b + 3);
        acc0.x += s0 * xv[j].x; acc0.y += s0 * xv[j].y;
        acc1.x += s1 * xv[j].x; acc1.y += s1 * xv[j].y;
        acc2.x += s2 * xv[j].x; acc2.y += s2 * xv[j].y;
        acc3.x += s3 * xv[j].x; acc3.y += s3 * xv[j].y;
      }
    }
    c = cnx; cn = cn2; ed = ed2;
  }

  // rowsum per head: butterfly over lanes with equal (lane&3)
  rsum += __shfl_xor(rsum, 4);
  rsum += __shfl_xor(rsum, 8);
  rsum += __shfl_xor(rsum, 16);
  rsum += __shfl_xor(rsum, 32);
  float r0 = readlane_f(rsum, 0), r1 = readlane_f(rsum, 1);
  float r2 = readlane_f(rsum, 2), r3 = readlane_f(rsum, 3);

  const float2* W2 = (const float2*)W;
  float2 o{0.f, 0.f};
  {
    float2 wv = W2[0 * 64 + lane];
    float hx = wv.x * acc0.x / r0, hy = wv.y * acc0.y / r0;
    o.x += (hx > 0.f) ? hx : expm1f(hx); o.y += (hy > 0.f) ? hy : expm1f(hy);
  }
  {
    float2 wv = W2[1 * 64 + lane];
    float hx = wv.x * acc1.x / r1, hy = wv.y * acc1.y / r1;
    o.x += (hx > 0.f) ? hx : expm1f(hx); o.y += (hy > 0.f) ? hy : expm1f(hy);
  }
  {
    float2 wv = W2[2 * 64 + lane];
    float hx = wv.x * acc2.x / r2, hy = wv.y * acc2.y / r2;
    o.x += (hx > 0.f) ? hx : expm1f(hx); o.y += (hy > 0.f) ? hy : expm1f(hy);
  }
  {
    float2 wv = W2[3 * 64 + lane];
    float hx = wv.x * acc3.x / r3, hy = wv.y * acc3.y / r3;
    o.x += (hx > 0.f) ? hx : expm1f(hx); o.y += (hy > 0.f) ? hy : expm1f(hy);
  }
  o.x *= 0.25f; o.y *= 0.25f;
  ((float2*)out)[(size_t)node * 64 + lane] = o;
}

extern "C" void kernel_launch(void* const* d_in, const int* in_sizes, int n_in,
                              void* d_out, int out_size, void* d_ws, size_t ws_size,
                              hipStream_t stream) {
  const float* x   = (const float*)d_in[0];
  const int*   edg = (const int*)d_in[1];
  const float* adj = (const float*)d_in[2];
  const float* W   = (const float*)d_in[3];
  const float* a   = (const float*)d_in[4];
  float* out = (float*)d_out;

  int E = in_sizes[2];
  int n = in_sizes[0] / FDIM;
  const int* src = edg;
  const int* dst = edg + E;

  auto align = [](size_t v) { return (v + 255) & ~(size_t)255; };
  char* ws = (char*)d_ws;
  int*   counts      = (int*)ws;   ws += align((size_t)n * 4);
  int*   row_ptr     = (int*)ws;   ws += align((size_t)(n + 1) * 4);
  int*   cursor      = (int*)ws;   ws += align((size_t)n * 4);
  int*   partials    = (int*)ws;   ws += align(SCAN_THREADS * 4);
  int2*  edge_sorted = (int2*)ws;  ws += align((size_t)E * 8);
  float* s_src       = (float*)ws; ws += align((size_t)n * HEADS * 4);
  float* s_dst       = (float*)ws; ws += align((size_t)n * HEADS * 4);

  int P = (n + SCAN_CHUNK - 1) / SCAN_CHUNK;   // <= SCAN_THREADS

  score_kernel<<<(n + 3) / 4, 256, 0, stream>>>(x, W, a, s_src, s_dst, counts, n);
  hist_kernel<<<((E >> 2) + 255) / 256, 256, 0, stream>>>(src, counts, E);
  scan1_kernel<<<P, SCAN_THREADS, 0, stream>>>(counts, partials, n);
  scan3_kernel<<<P, SCAN_THREADS, 0, stream>>>(counts, partials, row_ptr, cursor, n, P, E);
  scatter_kernel<<<(E + 255) / 256, 256, 0, stream>>>(src, dst, adj, cursor, edge_sorted, E);
  aggregate_kernel<<<(n + 3) / 4, 256, 0, stream>>>(x, W, s_src, s_dst, row_ptr,
                                                    edge_sorted, out, n);
}

// Round 5
// 450.815 us; speedup vs baseline: 1.2192x; 1.0192x over previous
//
#include <hip/hip_runtime.h>

#define FDIM   128
#define HEADS  4
#define ALPHA  0.2f
#define CN     16            // edge chunk per wave iteration

#define SCAN_CHUNK   1024
#define SCAN_THREADS 256

__device__ __forceinline__ float readlane_f(float v, int lane) {
  return __int_as_float(__builtin_amdgcn_readlane(__float_as_int(v), lane));
}

// ---------------- per-node scores + bf16-pack of x: one wave per node --------
// xb[node*64+lane] = packed bf16x2 of features (2*lane, 2*lane+1), RNE rounding.
// Also zeroes counts[] (stream order guarantees completion before hist_kernel).
__global__ __launch_bounds__(256) void score_kernel(
    const float* __restrict__ x, const float* __restrict__ W,
    const float* __restrict__ a, float* __restrict__ s_src,
    float* __restrict__ s_dst, unsigned int* __restrict__ xb,
    int* __restrict__ counts, int n) {
  int lane = threadIdx.x & 63;
  int node = (blockIdx.x << 2) + (threadIdx.x >> 6);
  if (node >= n) return;
  if (lane == 0) counts[node] = 0;
  const float2* x2 = (const float2*)x;
  const float2* W2 = (const float2*)W;
  const float2* a2 = (const float2*)a;
  float2 xv = x2[(size_t)node * 64 + lane];

  // bf16 pack (round-to-nearest-even)
  unsigned int u0 = __float_as_uint(xv.x);
  unsigned int u1 = __float_as_uint(xv.y);
  u0 += 0x7fffu + ((u0 >> 16) & 1u);
  u1 += 0x7fffu + ((u1 >> 16) & 1u);
  xb[(size_t)node * 64 + lane] = (u0 >> 16) | (u1 & 0xffff0000u);

#pragma unroll
  for (int k = 0; k < HEADS; k++) {
    float2 wv = W2[k * 64 + lane];
    float hx = xv.x * wv.x, hy = xv.y * wv.y;
    float2 as_ = a2[k * 128 + lane];        // a[k, 0:F]
    float2 ad_ = a2[k * 128 + 64 + lane];   // a[k, F:2F]
    float rs = hx * as_.x + hy * as_.y;
    float rd = hx * ad_.x + hy * ad_.y;
#pragma unroll
    for (int off = 32; off > 0; off >>= 1) {
      rs += __shfl_down(rs, off);
      rd += __shfl_down(rd, off);
    }
    if (lane == 0) {
      s_src[node * HEADS + k] = rs;
      s_dst[node * HEADS + k] = rd;
    }
  }
}

// ---------------- counting sort: histogram (int4 reads) ----------------
__global__ __launch_bounds__(256) void hist_kernel(const int* __restrict__ src,
                                                   int* __restrict__ counts, int E) {
  int i = blockIdx.x * 256 + threadIdx.x;
  int nq = E >> 2;
  if (i < nq) {
    int4 v = ((const int4*)src)[i];
    atomicAdd(&counts[v.x], 1);
    atomicAdd(&counts[v.y], 1);
    atomicAdd(&counts[v.z], 1);
    atomicAdd(&counts[v.w], 1);
  }
  if (i < (E & 3)) atomicAdd(&counts[src[(nq << 2) + i]], 1);
}

// ---------------- scan step 1: per-chunk sums ----------------
__global__ __launch_bounds__(SCAN_THREADS) void scan1_kernel(const int* __restrict__ counts,
                                                             int* __restrict__ partials, int n) {
  __shared__ int lds[SCAN_THREADS];
  int b = blockIdx.x, t = threadIdx.x;
  int base = b * SCAN_CHUNK + t * 4;
  int s = 0;
#pragma unroll
  for (int j = 0; j < 4; j++) {
    int i = base + j;
    s += (i < n) ? counts[i] : 0;
  }
  lds[t] = s;
  __syncthreads();
  for (int off = SCAN_THREADS / 2; off > 0; off >>= 1) {
    if (t < off) lds[t] += lds[t + off];
    __syncthreads();
  }
  if (t == 0) partials[b] = lds[0];
}

// ---------------- scan step 2+3 fused: row_ptr + cursor ----------------
__global__ __launch_bounds__(SCAN_THREADS) void scan3_kernel(
    const int* __restrict__ counts, const int* __restrict__ partials,
    int* __restrict__ row_ptr, int* __restrict__ cursor, int n, int P, int Etot) {
  __shared__ int sred[SCAN_THREADS];
  __shared__ int lds[SCAN_THREADS];
  int b = blockIdx.x, t = threadIdx.x;

  sred[t] = (t < P && t < b) ? partials[t] : 0;
  __syncthreads();
  for (int off = SCAN_THREADS / 2; off > 0; off >>= 1) {
    if (t < off) sred[t] += sred[t + off];
    __syncthreads();
  }
  int pref = sred[0];
  __syncthreads();

  int base = b * SCAN_CHUNK + t * 4;
  int v[4];
  int s = 0;
#pragma unroll
  for (int j = 0; j < 4; j++) {
    int i = base + j;
    v[j] = (i < n) ? counts[i] : 0;
    s += v[j];
  }
  int mine = s;
  lds[t] = s;
  __syncthreads();
  for (int off = 1; off < SCAN_THREADS; off <<= 1) {
    int xv = (t >= off) ? lds[t - off] : 0;
    __syncthreads();
    lds[t] += xv;
    __syncthreads();
  }
  int run = pref + (lds[t] - mine);
#pragma unroll
  for (int j = 0; j < 4; j++) {
    int i = base + j;
    if (i < n) {
      row_ptr[i] = run;
      cursor[i]  = run;
    }
    run += v[j];
  }
  if (b == 0 && t == 0) row_ptr[n] = Etot;
}

// ---------------- counting sort: scatter (packed 8B payload) ----------------
__global__ __launch_bounds__(256) void scatter_kernel(
    const int* __restrict__ src, const int* __restrict__ dst,
    const float* __restrict__ adj, int* __restrict__ cursor,
    int2* __restrict__ edge_sorted, int E) {
  int i = blockIdx.x * 256 + threadIdx.x;
  if (i >= E) return;
  int s = src[i];
  int pos = atomicAdd(&cursor[s], 1);
  int2 pk;
  pk.x = dst[i];
  pk.y = __float_as_int(adj[i]);
  edge_sorted[pos] = pk;
}

// ---------------- main aggregation: wave/node, bf16 row gather (4B/lane) -----
// Padding invariant: inactive edge slots carry ed={0,0} -> ev = exp(s)*0 = 0,
// dst = 0 -> the padded fmacs add exactly 0 using a (cached) load of row 0.
__global__ __launch_bounds__(256, 8) void aggregate_kernel(
    const unsigned int* __restrict__ xb, const float* __restrict__ W,
    const float* __restrict__ s_src, const float* __restrict__ s_dst,
    const int* __restrict__ row_ptr, const int2* __restrict__ edge_sorted,
    float* __restrict__ out, int n) {
  int lane = threadIdx.x & 63;
  int node = (blockIdx.x << 2) + (threadIdx.x >> 6);
  if (node >= n) return;                 // wave-uniform; no barriers anywhere
  int beg = row_ptr[node], end = row_ptr[node + 1];
  int e = lane >> 2;                     // edge slot 0..15
  int k = lane & 3;                      // head
  float ssrc_k = s_src[node * HEADS + k];

  float2 acc0{0.f,0.f}, acc1{0.f,0.f}, acc2{0.f,0.f}, acc3{0.f,0.f};
  float rsum = 0.f;

  int c = beg;
  int cn = end - c; if (cn > CN) cn = CN;
  int2 ed{0, 0};
  if (e < cn) ed = edge_sorted[c + e];

  while (c < end) {
    float s = ssrc_k + s_dst[ed.x * HEADS + k];
    s = (s >= 0.f) ? s : ALPHA * s;
    float ev = __expf(s) * __int_as_float(ed.y);
    rsum += ev;

    // prefetch next chunk's payload
    int cnx = c + CN;
    int cn2 = end - cnx; if (cn2 > CN) cn2 = CN;
    int2 ed2{0, 0};
    if (cnx < end && e < cn2) ed2 = edge_sorted[cnx + e];

    int gmax = (cn + 7) & ~7;            // 8 or 16
    for (int g = 0; g < gmax; g += 8) {
      int dd[8];
      unsigned int xw[8];
#pragma unroll
      for (int j = 0; j < 8; j++)
        dd[j] = __builtin_amdgcn_readlane(ed.x, (g + j) * 4);
#pragma unroll
      for (int j = 0; j < 8; j++)
        xw[j] = xb[(unsigned)(dd[j] << 6) + lane];   // row = 64 dwords
#pragma unroll
      for (int j = 0; j < 8; j++) {
        int b = (g + j) * 4;
        float s0 = readlane_f(ev, b + 0);
        float s1 = readlane_f(ev, b + 1);
        float s2 = readlane_f(ev, b + 2);
        float s3 = readlane_f(ev, b + 3);
        float xlo = __uint_as_float(xw[j] << 16);          // feature 2*lane
        float xhi = __uint_as_float(xw[j] & 0xffff0000u);  // feature 2*lane+1
        acc0.x += s0 * xlo; acc0.y += s0 * xhi;
        acc1.x += s1 * xlo; acc1.y += s1 * xhi;
        acc2.x += s2 * xlo; acc2.y += s2 * xhi;
        acc3.x += s3 * xlo; acc3.y += s3 * xhi;
      }
    }
    c = cnx; cn = cn2; ed = ed2;
  }

  // rowsum per head: butterfly over lanes with equal (lane&3)
  rsum += __shfl_xor(rsum, 4);
  rsum += __shfl_xor(rsum, 8);
  rsum += __shfl_xor(rsum, 16);
  rsum += __shfl_xor(rsum, 32);
  float r0 = readlane_f(rsum, 0), r1 = readlane_f(rsum, 1);
  float r2 = readlane_f(rsum, 2), r3 = readlane_f(rsum, 3);

  const float2* W2 = (const float2*)W;
  float2 o{0.f, 0.f};
  {
    float2 wv = W2[0 * 64 + lane];
    float hx = wv.x * acc0.x / r0, hy = wv.y * acc0.y / r0;
    o.x += (hx > 0.f) ? hx : expm1f(hx); o.y += (hy > 0.f) ? hy : expm1f(hy);
  }
  {
    float2 wv = W2[1 * 64 + lane];
    float hx = wv.x * acc1.x / r1, hy = wv.y * acc1.y / r1;
    o.x += (hx > 0.f) ? hx : expm1f(hx); o.y += (hy > 0.f) ? hy : expm1f(hy);
  }
  {
    float2 wv = W2[2 * 64 + lane];
    float hx = wv.x * acc2.x / r2, hy = wv.y * acc2.y / r2;
    o.x += (hx > 0.f) ? hx : expm1f(hx); o.y += (hy > 0.f) ? hy : expm1f(hy);
  }
  {
    float2 wv = W2[3 * 64 + lane];
    float hx = wv.x * acc3.x / r3, hy = wv.y * acc3.y / r3;
    o.x += (hx > 0.f) ? hx : expm1f(hx); o.y += (hy > 0.f) ? hy : expm1f(hy);
  }
  o.x *= 0.25f; o.y *= 0.25f;
  ((float2*)out)[(size_t)node * 64 + lane] = o;
}

extern "C" void kernel_launch(void* const* d_in, const int* in_sizes, int n_in,
                              void* d_out, int out_size, void* d_ws, size_t ws_size,
                              hipStream_t stream) {
  const float* x   = (const float*)d_in[0];
  const int*   edg = (const int*)d_in[1];
  const float* adj = (const float*)d_in[2];
  const float* W   = (const float*)d_in[3];
  const float* a   = (const float*)d_in[4];
  float* out = (float*)d_out;

  int E = in_sizes[2];
  int n = in_sizes[0] / FDIM;
  const int* src = edg;
  const int* dst = edg + E;

  auto align = [](size_t v) { return (v + 255) & ~(size_t)255; };
  char* ws = (char*)d_ws;
  int*   counts      = (int*)ws;          ws += align((size_t)n * 4);
  int*   row_ptr     = (int*)ws;          ws += align((size_t)(n + 1) * 4);
  int*   cursor      = (int*)ws;          ws += align((size_t)n * 4);
  int*   partials    = (int*)ws;          ws += align(SCAN_THREADS * 4);
  int2*  edge_sorted = (int2*)ws;         ws += align((size_t)E * 8);
  float* s_src       = (float*)ws;        ws += align((size_t)n * HEADS * 4);
  float* s_dst       = (float*)ws;        ws += align((size_t)n * HEADS * 4);
  unsigned int* xb   = (unsigned int*)ws; ws += align((size_t)n * 64 * 4);

  int P = (n + SCAN_CHUNK - 1) / SCAN_CHUNK;   // <= SCAN_THREADS

  score_kernel<<<(n + 3) / 4, 256, 0, stream>>>(x, W, a, s_src, s_dst, xb, counts, n);
  hist_kernel<<<((E >> 2) + 255) / 256, 256, 0, stream>>>(src, counts, E);
  scan1_kernel<<<P, SCAN_THREADS, 0, stream>>>(counts, partials, n);
  scan3_kernel<<<P, SCAN_THREADS, 0, stream>>>(counts, partials, row_ptr, cursor, n, P, E);
  scatter_kernel<<<(E + 255) / 256, 256, 0, stream>>>(src, dst, adj, cursor, edge_sorted, E);
  aggregate_kernel<<<(n + 3) / 4, 256, 0, stream>>>(xb, W, s_src, s_dst, row_ptr,
                                                    edge_sorted, out, n);
}

// Round 6
// 422.224 us; speedup vs baseline: 1.3017x; 1.0677x over previous
//
#include <hip/hip_runtime.h>

#define FDIM   128
#define HEADS  4
#define ALPHA  0.2f
#define CN     32            // edge chunk per wave iteration

#define SCAN_CHUNK   1024
#define SCAN_THREADS 256

typedef float v2f __attribute__((ext_vector_type(2)));

__device__ __forceinline__ float readlane_f(float v, int lane) {
  return __int_as_float(__builtin_amdgcn_readlane(__float_as_int(v), lane));
}

// ---------------- per-node scores + bf16-pack of x: one wave per node --------
__global__ __launch_bounds__(256) void score_kernel(
    const float* __restrict__ x, const float* __restrict__ W,
    const float* __restrict__ a, float* __restrict__ s_src,
    float* __restrict__ s_dst, unsigned int* __restrict__ xb,
    int* __restrict__ counts, int n) {
  int lane = threadIdx.x & 63;
  int node = (blockIdx.x << 2) + (threadIdx.x >> 6);
  if (node >= n) return;
  if (lane == 0) counts[node] = 0;
  const float2* x2 = (const float2*)x;
  const float2* W2 = (const float2*)W;
  const float2* a2 = (const float2*)a;
  float2 xv = x2[(size_t)node * 64 + lane];

  // bf16 pack (round-to-nearest-even)
  unsigned int u0 = __float_as_uint(xv.x);
  unsigned int u1 = __float_as_uint(xv.y);
  u0 += 0x7fffu + ((u0 >> 16) & 1u);
  u1 += 0x7fffu + ((u1 >> 16) & 1u);
  xb[(size_t)node * 64 + lane] = (u0 >> 16) | (u1 & 0xffff0000u);

#pragma unroll
  for (int k = 0; k < HEADS; k++) {
    float2 wv = W2[k * 64 + lane];
    float hx = xv.x * wv.x, hy = xv.y * wv.y;
    float2 as_ = a2[k * 128 + lane];        // a[k, 0:F]
    float2 ad_ = a2[k * 128 + 64 + lane];   // a[k, F:2F]
    float rs = hx * as_.x + hy * as_.y;
    float rd = hx * ad_.x + hy * ad_.y;
#pragma unroll
    for (int off = 32; off > 0; off >>= 1) {
      rs += __shfl_down(rs, off);
      rd += __shfl_down(rd, off);
    }
    if (lane == 0) {
      s_src[node * HEADS + k] = rs;
      s_dst[node * HEADS + k] = rd;
    }
  }
}

// ---------------- counting sort: histogram (int4 reads) ----------------
__global__ __launch_bounds__(256) void hist_kernel(const int* __restrict__ src,
                                                   int* __restrict__ counts, int E) {
  int i = blockIdx.x * 256 + threadIdx.x;
  int nq = E >> 2;
  if (i < nq) {
    int4 v = ((const int4*)src)[i];
    atomicAdd(&counts[v.x], 1);
    atomicAdd(&counts[v.y], 1);
    atomicAdd(&counts[v.z], 1);
    atomicAdd(&counts[v.w], 1);
  }
  if (i < (E & 3)) atomicAdd(&counts[src[(nq << 2) + i]], 1);
}

// ---------------- scan step 1: per-chunk sums ----------------
__global__ __launch_bounds__(SCAN_THREADS) void scan1_kernel(const int* __restrict__ counts,
                                                             int* __restrict__ partials, int n) {
  __shared__ int lds[SCAN_THREADS];
  int b = blockIdx.x, t = threadIdx.x;
  int base = b * SCAN_CHUNK + t * 4;
  int s = 0;
#pragma unroll
  for (int j = 0; j < 4; j++) {
    int i = base + j;
    s += (i < n) ? counts[i] : 0;
  }
  lds[t] = s;
  __syncthreads();
  for (int off = SCAN_THREADS / 2; off > 0; off >>= 1) {
    if (t < off) lds[t] += lds[t + off];
    __syncthreads();
  }
  if (t == 0) partials[b] = lds[0];
}

// ---------------- scan step 2+3 fused: row_ptr + cursor ----------------
__global__ __launch_bounds__(SCAN_THREADS) void scan3_kernel(
    const int* __restrict__ counts, const int* __restrict__ partials,
    int* __restrict__ row_ptr, int* __restrict__ cursor, int n, int P, int Etot) {
  __shared__ int sred[SCAN_THREADS];
  __shared__ int lds[SCAN_THREADS];
  int b = blockIdx.x, t = threadIdx.x;

  sred[t] = (t < P && t < b) ? partials[t] : 0;
  __syncthreads();
  for (int off = SCAN_THREADS / 2; off > 0; off >>= 1) {
    if (t < off) sred[t] += sred[t + off];
    __syncthreads();
  }
  int pref = sred[0];
  __syncthreads();

  int base = b * SCAN_CHUNK + t * 4;
  int v[4];
  int s = 0;
#pragma unroll
  for (int j = 0; j < 4; j++) {
    int i = base + j;
    v[j] = (i < n) ? counts[i] : 0;
    s += v[j];
  }
  int mine = s;
  lds[t] = s;
  __syncthreads();
  for (int off = 1; off < SCAN_THREADS; off <<= 1) {
    int xv = (t >= off) ? lds[t - off] : 0;
    __syncthreads();
    lds[t] += xv;
    __syncthreads();
  }
  int run = pref + (lds[t] - mine);
#pragma unroll
  for (int j = 0; j < 4; j++) {
    int i = base + j;
    if (i < n) {
      row_ptr[i] = run;
      cursor[i]  = run;
    }
    run += v[j];
  }
  if (b == 0 && t == 0) row_ptr[n] = Etot;
}

// ---------------- counting sort: scatter (packed 8B payload) ----------------
__global__ __launch_bounds__(256) void scatter_kernel(
    const int* __restrict__ src, const int* __restrict__ dst,
    const float* __restrict__ adj, int* __restrict__ cursor,
    int2* __restrict__ edge_sorted, int E) {
  int i = blockIdx.x * 256 + threadIdx.x;
  if (i >= E) return;
  int s = src[i];
  int pos = atomicAdd(&cursor[s], 1);
  int2 pk;
  pk.x = dst[i];
  pk.y = __float_as_int(adj[i]);
  edge_sorted[pos] = pk;
}

// ---------------- main aggregation: wave/node, LDS ev-broadcast, pk-fma ------
// Padding invariant: inactive edge slots carry ed={0,0} -> ev = exp(s)*0 = 0,
// dst = 0 -> the padded fmacs add exactly 0 using a (cached) load of row 0.
// evbuf is wave-private (no __syncthreads; same-wave LDS ordering suffices).
__global__ __launch_bounds__(256, 8) void aggregate_kernel(
    const unsigned int* __restrict__ xb, const float* __restrict__ W,
    const float* __restrict__ s_src, const float* __restrict__ s_dst,
    const int* __restrict__ row_ptr, const int2* __restrict__ edge_sorted,
    float* __restrict__ out, int n) {
  __shared__ float evbuf[4][2 * 64];      // [wave][edge*4 + head], slots 0..127
  int lane = threadIdx.x & 63;
  int wid  = threadIdx.x >> 6;
  int node = (blockIdx.x << 2) + wid;
  if (node >= n) return;                  // wave-uniform
  int beg = row_ptr[node], end = row_ptr[node + 1];
  int e = lane >> 2;                      // edge slot 0..15 (per half-chunk)
  int k = lane & 3;                       // head
  float ssrc_k = s_src[node * HEADS + k];

  v2f acc0 = {0.f, 0.f}, acc1 = {0.f, 0.f}, acc2 = {0.f, 0.f}, acc3 = {0.f, 0.f};
  float rsum = 0.f;

  // one 8-edge group: 8 gathers in flight, evs via wave-uniform LDS broadcast
  auto group8 = [&](int edx, int roff, int slot0) {
    int dd[8];
    unsigned int xw[8];
#pragma unroll
    for (int j = 0; j < 8; j++)
      dd[j] = __builtin_amdgcn_readlane(edx, (roff + j) * 4);
#pragma unroll
    for (int j = 0; j < 8; j++)
      xw[j] = xb[(unsigned)(dd[j] << 6) + lane];
#pragma unroll
    for (int j = 0; j < 8; j++) {
      const float4 s4 = *(const float4*)&evbuf[wid][(slot0 + j) * 4];
      v2f xv;
      xv.x = __uint_as_float(xw[j] << 16);          // feature 2*lane
      xv.y = __uint_as_float(xw[j] & 0xffff0000u);  // feature 2*lane+1
      acc0 += s4.x * xv;
      acc1 += s4.y * xv;
      acc2 += s4.z * xv;
      acc3 += s4.w * xv;
    }
  };

  int c = beg;
  int cn = end - c; if (cn > CN) cn = CN;
  int2 eda{0, 0}, edb{0, 0};
  if (e < cn)      eda = edge_sorted[c + e];
  if (16 + e < cn) edb = edge_sorted[c + 16 + e];

  while (c < end) {
    // e-values for 32 edges (2 per lane); padded slots give exactly 0
    float sa = ssrc_k + s_dst[eda.x * HEADS + k];
    sa = (sa >= 0.f) ? sa : ALPHA * sa;
    float eva = __expf(sa) * __int_as_float(eda.y);
    float sb = ssrc_k + s_dst[edb.x * HEADS + k];
    sb = (sb >= 0.f) ? sb : ALPHA * sb;
    float evb = __expf(sb) * __int_as_float(edb.y);
    rsum += eva + evb;
    evbuf[wid][lane] = eva;               // slots  0..63  = edges  0..15
    evbuf[wid][64 + lane] = evb;          // slots 64..127 = edges 16..31

    // prefetch next chunk's payload
    int cnx = c + CN;
    int cn2 = end - cnx; if (cn2 > CN) cn2 = CN;
    int2 eda2{0, 0}, edb2{0, 0};
    if (cnx < end) {
      if (e < cn2)      eda2 = edge_sorted[cnx + e];
      if (16 + e < cn2) edb2 = edge_sorted[cnx + 16 + e];
    }

    group8(eda.x, 0, 0);
    if (cn > 8)  group8(eda.x, 8, 8);
    if (cn > 16) group8(edb.x, 0, 16);
    if (cn > 24) group8(edb.x, 8, 24);

    c = cnx; cn = cn2; eda = eda2; edb = edb2;
  }

  // rowsum per head: butterfly over lanes with equal (lane&3)
  rsum += __shfl_xor(rsum, 4);
  rsum += __shfl_xor(rsum, 8);
  rsum += __shfl_xor(rsum, 16);
  rsum += __shfl_xor(rsum, 32);
  float r0 = readlane_f(rsum, 0), r1 = readlane_f(rsum, 1);
  float r2 = readlane_f(rsum, 2), r3 = readlane_f(rsum, 3);

  const float2* W2 = (const float2*)W;
  float2 o{0.f, 0.f};
  {
    float2 wv = W2[0 * 64 + lane];
    float hx = wv.x * acc0.x / r0, hy = wv.y * acc0.y / r0;
    o.x += (hx > 0.f) ? hx : expm1f(hx); o.y += (hy > 0.f) ? hy : expm1f(hy);
  }
  {
    float2 wv = W2[1 * 64 + lane];
    float hx = wv.x * acc1.x / r1, hy = wv.y * acc1.y / r1;
    o.x += (hx > 0.f) ? hx : expm1f(hx); o.y += (hy > 0.f) ? hy : expm1f(hy);
  }
  {
    float2 wv = W2[2 * 64 + lane];
    float hx = wv.x * acc2.x / r2, hy = wv.y * acc2.y / r2;
    o.x += (hx > 0.f) ? hx : expm1f(hx); o.y += (hy > 0.f) ? hy : expm1f(hy);
  }
  {
    float2 wv = W2[3 * 64 + lane];
    float hx = wv.x * acc3.x / r3, hy = wv.y * acc3.y / r3;
    o.x += (hx > 0.f) ? hx : expm1f(hx); o.y += (hy > 0.f) ? hy : expm1f(hy);
  }
  o.x *= 0.25f; o.y *= 0.25f;
  ((float2*)out)[(size_t)node * 64 + lane] = o;
}

extern "C" void kernel_launch(void* const* d_in, const int* in_sizes, int n_in,
                              void* d_out, int out_size, void* d_ws, size_t ws_size,
                              hipStream_t stream) {
  const float* x   = (const float*)d_in[0];
  const int*   edg = (const int*)d_in[1];
  const float* adj = (const float*)d_in[2];
  const float* W   = (const float*)d_in[3];
  const float* a   = (const float*)d_in[4];
  float* out = (float*)d_out;

  int E = in_sizes[2];
  int n = in_sizes[0] / FDIM;
  const int* src = edg;
  const int* dst = edg + E;

  auto align = [](size_t v) { return (v + 255) & ~(size_t)255; };
  char* ws = (char*)d_ws;
  int*   counts      = (int*)ws;          ws += align((size_t)n * 4);
  int*   row_ptr     = (int*)ws;          ws += align((size_t)(n + 1) * 4);
  int*   cursor      = (int*)ws;          ws += align((size_t)n * 4);
  int*   partials    = (int*)ws;          ws += align(SCAN_THREADS * 4);
  int2*  edge_sorted = (int2*)ws;         ws += align((size_t)E * 8);
  float* s_src       = (float*)ws;        ws += align((size_t)n * HEADS * 4);
  float* s_dst       = (float*)ws;        ws += align((size_t)n * HEADS * 4);
  unsigned int* xb   = (unsigned int*)ws; ws += align((size_t)n * 64 * 4);

  int P = (n + SCAN_CHUNK - 1) / SCAN_CHUNK;   // <= SCAN_THREADS

  score_kernel<<<(n + 3) / 4, 256, 0, stream>>>(x, W, a, s_src, s_dst, xb, counts, n);
  hist_kernel<<<((E >> 2) + 255) / 256, 256, 0, stream>>>(src, counts, E);
  scan1_kernel<<<P, SCAN_THREADS, 0, stream>>>(counts, partials, n);
  scan3_kernel<<<P, SCAN_THREADS, 0, stream>>>(counts, partials, row_ptr, cursor, n, P, E);
  scatter_kernel<<<(E + 255) / 256, 256, 0, stream>>>(src, dst, adj, cursor, edge_sorted, E);
  aggregate_kernel<<<(n + 3) / 4, 256, 0, stream>>>(xb, W, s_src, s_dst, row_ptr,
                                                    edge_sorted, out, n);
}

// Round 7
// 328.477 us; speedup vs baseline: 1.6732x; 1.2854x over previous
//
#include <hip/hip_runtime.h>

#define FDIM   128
#define HEADS  4
#define ALPHA  0.2f
#define DMASK  0x03FFFFFF     // low 26 bits = dst
#define PT     4096           // partition tile (edges per block)
#define NBMAX  1568           // max fine buckets supported by static LDS

typedef float v2f __attribute__((ext_vector_type(2)));

__device__ __forceinline__ float readlane_f(float v, int lane) {
  return __int_as_float(__builtin_amdgcn_readlane(__float_as_int(v), lane));
}

// ---------------- per-node scores + bf16-pack of x: one wave per node --------
__global__ __launch_bounds__(256) void score_kernel(
    const float* __restrict__ x, const float* __restrict__ W,
    const float* __restrict__ a, float* __restrict__ s_src,
    float* __restrict__ s_dst, unsigned int* __restrict__ xb, int n) {
  int lane = threadIdx.x & 63;
  int node = (blockIdx.x << 2) + (threadIdx.x >> 6);
  if (node >= n) return;
  const float2* x2 = (const float2*)x;
  const float2* W2 = (const float2*)W;
  const float2* a2 = (const float2*)a;
  float2 xv = x2[(size_t)node * 64 + lane];

  // bf16 pack (round-to-nearest-even)
  unsigned int u0 = __float_as_uint(xv.x);
  unsigned int u1 = __float_as_uint(xv.y);
  u0 += 0x7fffu + ((u0 >> 16) & 1u);
  u1 += 0x7fffu + ((u1 >> 16) & 1u);
  xb[(size_t)node * 64 + lane] = (u0 >> 16) | (u1 & 0xffff0000u);

#pragma unroll
  for (int k = 0; k < HEADS; k++) {
    float2 wv = W2[k * 64 + lane];
    float hx = xv.x * wv.x, hy = xv.y * wv.y;
    float2 as_ = a2[k * 128 + lane];        // a[k, 0:F]
    float2 ad_ = a2[k * 128 + 64 + lane];   // a[k, F:2F]
    float rs = hx * as_.x + hy * as_.y;
    float rd = hx * ad_.x + hy * ad_.y;
#pragma unroll
    for (int off = 32; off > 0; off >>= 1) {
      rs += __shfl_down(rs, off);
      rd += __shfl_down(rd, off);
    }
    if (lane == 0) {
      s_src[node * HEADS + k] = rs;
      s_dst[node * HEADS + k] = rd;
    }
  }
}

// ---------------- fine-bucket histogram (bucket = src>>6), LDS pre-agg -------
__global__ __launch_bounds__(256) void hist_kernel(const int* __restrict__ src,
                                                   int* __restrict__ hist,
                                                   int E, int NB) {
  __shared__ int h[NBMAX];
  int t = threadIdx.x;
  for (int i = t; i < NB; i += 256) h[i] = 0;
  __syncthreads();
  int base = blockIdx.x * 8192;
#pragma unroll 4
  for (int j = 0; j < 32; j++) {
    int i = base + j * 256 + t;
    if (i < E) atomicAdd(&h[src[i] >> 6], 1);
  }
  __syncthreads();
  for (int i = t; i < NB; i += 256)
    if (h[i]) atomicAdd(&hist[i], h[i]);
}

// ---------------- exclusive scan of NB (<=2048) bucket counts: 1 block -------
__global__ __launch_bounds__(256) void scan_kernel(const int* __restrict__ hist,
                                                   int* __restrict__ fine_ptr,
                                                   int* __restrict__ cursor,
                                                   int NB, int E) {
  __shared__ int lds[256];
  int t = threadIdx.x;
  int loc[8];
  int s = 0;
#pragma unroll
  for (int j = 0; j < 8; j++) {
    int idx = t * 8 + j;
    loc[j] = (idx < NB) ? hist[idx] : 0;
    s += loc[j];
  }
  lds[t] = s;
  __syncthreads();
  for (int off = 1; off < 256; off <<= 1) {
    int xv = (t >= off) ? lds[t - off] : 0;
    __syncthreads();
    lds[t] += xv;
    __syncthreads();
  }
  int run = lds[t] - s;   // exclusive prefix of this thread's segment
#pragma unroll
  for (int j = 0; j < 8; j++) {
    int idx = t * 8 + j;
    if (idx < NB) {
      fine_ptr[idx] = run;
      cursor[idx]   = run;
    }
    run += loc[j];
  }
  if (t == 0) fine_ptr[NB] = E;
}

// ---------------- partition: tile-sort 4096 edges by fine bucket in LDS ------
// Writes bucket-contiguous runs (consecutive threads -> consecutive addresses)
// instead of random 8B scatters.  Payload: pk.x = (src&63)<<26 | dst, pk.y=adj.
__global__ __launch_bounds__(256) void partition_kernel(
    const int* __restrict__ src, const int* __restrict__ dst,
    const float* __restrict__ adj, int* __restrict__ cursor,
    int2* __restrict__ ebuf, int E, int NB) {
  __shared__ int h[NBMAX];               // per-tile bucket counts
  __shared__ int sc[NBMAX];              // tile-local exclusive offsets (then running)
  __shared__ int bg[NBMAX];              // reserved global bases
  __shared__ unsigned short keyarr[PT];  // bucket id per sorted slot
  __shared__ int2 es[PT];                // tile edges, bucket-sorted
  __shared__ int lds[256];

  int t = threadIdx.x;
  int base = blockIdx.x * PT;
  for (int i = t; i < NB; i += 256) h[i] = 0;
  __syncthreads();

  int ssrc[16];
#pragma unroll
  for (int j = 0; j < 16; j++) {
    int i = base + j * 256 + t;
    ssrc[j] = (i < E) ? src[i] : -1;
    if (ssrc[j] >= 0) atomicAdd(&h[ssrc[j] >> 6], 1);
  }
  __syncthreads();

  // in-block exclusive scan of h[0..NB)
  int loc[8];
  int s = 0;
#pragma unroll
  for (int j = 0; j < 8; j++) {
    int idx = t * 8 + j;
    loc[j] = (idx < NB) ? h[idx] : 0;
    s += loc[j];
  }
  lds[t] = s;
  __syncthreads();
  for (int off = 1; off < 256; off <<= 1) {
    int xv = (t >= off) ? lds[t - off] : 0;
    __syncthreads();
    lds[t] += xv;
    __syncthreads();
  }
  int run = lds[t] - s;
#pragma unroll
  for (int j = 0; j < 8; j++) {
    int idx = t * 8 + j;
    if (idx < NB) sc[idx] = run;
    run += loc[j];
  }
  __syncthreads();

  // reserve global ranges (one atomic per nonzero bucket per tile)
  for (int i = t; i < NB; i += 256)
    if (h[i]) bg[i] = atomicAdd(&cursor[i], h[i]);
  __syncthreads();

  // hand out tile-local slots (sc becomes running cursor), stage sorted in LDS
#pragma unroll
  for (int j = 0; j < 16; j++) {
    if (ssrc[j] >= 0) {
      int i = base + j * 256 + t;
      int k = ssrc[j] >> 6;
      int slot = atomicAdd(&sc[k], 1);
      int2 pk;
      pk.x = (int)(((unsigned)(ssrc[j] & 63) << 26) | (unsigned)dst[i]);
      pk.y = __float_as_int(adj[i]);
      es[slot] = pk;
      keyarr[slot] = (unsigned short)k;
    }
  }
  __syncthreads();

  // coalesced write-out: slot s2 -> global bg[k] + rank
  int tc = E - base; if (tc > PT) tc = PT;
  for (int s2 = t; s2 < tc; s2 += 256) {
    int k = keyarr[s2];
    int rank = s2 - (sc[k] - h[k]);   // sc is now inclusive end; sc-h = orig start
    ebuf[bg[k] + rank] = es[s2];
  }
}

// ---------------- aggregate: one block per 64-node bucket --------------------
// Loads bucket edges (coalesced), counting-sorts by src&63 in LDS, then each
// wave runs the per-node pipeline (LDS ev-broadcast + 8-deep bf16 row gather).
__global__ __launch_bounds__(256, 8) void aggregate_kernel(
    const unsigned int* __restrict__ xb, const float* __restrict__ W,
    const float* __restrict__ s_src, const float* __restrict__ s_dst,
    const int* __restrict__ fine_ptr, const int2* __restrict__ ebuf,
    float* __restrict__ out, int n) {
  __shared__ int2  es[2048];
  __shared__ float evbuf[4][64];
  __shared__ int   nbeg[65];
  __shared__ int   nrun[64];
  __shared__ int   h[64];

  int t = threadIdx.x, b = blockIdx.x;
  int lane = t & 63, wid = t >> 6;
  int beg = fine_ptr[b];
  int L   = fine_ptr[b + 1] - beg;

  if (t < 64) h[t] = 0;
  __syncthreads();
  for (int i = t; i < L; i += 256)
    atomicAdd(&h[(unsigned)ebuf[beg + i].x >> 26], 1);
  __syncthreads();
  if (t < 64) {   // wave-0 shfl inclusive scan of 64 counters
    int v = h[t];
#pragma unroll
    for (int off = 1; off < 64; off <<= 1) {
      int u = __shfl_up(v, off);
      if (lane >= off) v += u;
    }
    nbeg[t + 1] = v;
    nrun[t] = v - h[t];
    if (t == 0) nbeg[0] = 0;
  }
  __syncthreads();
  for (int i = t; i < L; i += 256) {
    int2 pk = ebuf[beg + i];
    int kk = (unsigned)pk.x >> 26;
    int slot = atomicAdd(&nrun[kk], 1);
    es[slot] = pk;
  }
  __syncthreads();

  int e = lane >> 2;                   // edge slot 0..15
  int k = lane & 3;                    // head
  const float2* W2 = (const float2*)W;
  float2 wv0 = W2[0 * 64 + lane], wv1 = W2[1 * 64 + lane];
  float2 wv2 = W2[2 * 64 + lane], wv3 = W2[3 * 64 + lane];

  for (int ni = 0; ni < 16; ni++) {
    int nl = wid * 16 + ni;
    int node = (b << 6) + nl;
    if (node >= n) break;              // wave-uniform
    int eb = nbeg[nl], cnt = nbeg[nl + 1] - eb;
    float ssrc_k = s_src[node * HEADS + k];

    v2f acc0 = {0.f,0.f}, acc1 = {0.f,0.f}, acc2 = {0.f,0.f}, acc3 = {0.f,0.f};
    float rsum = 0.f;

    auto group8 = [&](int dvv, int roff, int slot0) {
      int dd[8];
      unsigned int xw[8];
#pragma unroll
      for (int j = 0; j < 8; j++)
        dd[j] = __builtin_amdgcn_readlane(dvv, (roff + j) * 4);
#pragma unroll
      for (int j = 0; j < 8; j++)
        xw[j] = xb[(unsigned)(dd[j] << 6) + lane];
#pragma unroll
      for (int j = 0; j < 8; j++) {
        const float4 s4 = *(const float4*)&evbuf[wid][(slot0 + j) * 4];
        v2f xv;
        xv.x = __uint_as_float(xw[j] << 16);
        xv.y = __uint_as_float(xw[j] & 0xffff0000u);
        acc0 += s4.x * xv;
        acc1 += s4.y * xv;
        acc2 += s4.z * xv;
        acc3 += s4.w * xv;
      }
    };

    int c = 0;
    while (c < cnt) {
      int cn = cnt - c; if (cn > 16) cn = 16;
      int2 pk{0, 0};
      if (e < cn) pk = es[eb + c + e];
      int dv = pk.x & DMASK;
      float s = ssrc_k + s_dst[dv * HEADS + k];
      s = (s >= 0.f) ? s : ALPHA * s;
      float ev = __expf(s) * __int_as_float(pk.y);   // padded slots: adj=0 -> 0
      rsum += ev;
      evbuf[wid][lane] = ev;          // wave-private; in-order DS pipe, no barrier
      group8(dv, 0, 0);
      if (cn > 8) group8(dv, 8, 8);
      c += 16;
    }

    rsum += __shfl_xor(rsum, 4);
    rsum += __shfl_xor(rsum, 8);
    rsum += __shfl_xor(rsum, 16);
    rsum += __shfl_xor(rsum, 32);
    float r0 = readlane_f(rsum, 0), r1 = readlane_f(rsum, 1);
    float r2 = readlane_f(rsum, 2), r3 = readlane_f(rsum, 3);

    float2 o{0.f, 0.f};
    float hx, hy;
    hx = wv0.x * acc0.x / r0; hy = wv0.y * acc0.y / r0;
    o.x += (hx > 0.f) ? hx : expm1f(hx); o.y += (hy > 0.f) ? hy : expm1f(hy);
    hx = wv1.x * acc1.x / r1; hy = wv1.y * acc1.y / r1;
    o.x += (hx > 0.f) ? hx : expm1f(hx); o.y += (hy > 0.f) ? hy : expm1f(hy);
    hx = wv2.x * acc2.x / r2; hy = wv2.y * acc2.y / r2;
    o.x += (hx > 0.f) ? hx : expm1f(hx); o.y += (hy > 0.f) ? hy : expm1f(hy);
    hx = wv3.x * acc3.x / r3; hy = wv3.y * acc3.y / r3;
    o.x += (hx > 0.f) ? hx : expm1f(hx); o.y += (hy > 0.f) ? hy : expm1f(hy);
    o.x *= 0.25f; o.y *= 0.25f;
    ((float2*)out)[(size_t)node * 64 + lane] = o;
  }
}

extern "C" void kernel_launch(void* const* d_in, const int* in_sizes, int n_in,
                              void* d_out, int out_size, void* d_ws, size_t ws_size,
                              hipStream_t stream) {
  const float* x   = (const float*)d_in[0];
  const int*   edg = (const int*)d_in[1];
  const float* adj = (const float*)d_in[2];
  const float* W   = (const float*)d_in[3];
  const float* a   = (const float*)d_in[4];
  float* out = (float*)d_out;

  int E = in_sizes[2];
  int n = in_sizes[0] / FDIM;
  const int* src = edg;
  const int* dst = edg + E;
  int NB = (n + 63) >> 6;              // fine buckets of 64 nodes (<= NBMAX)

  auto align = [](size_t v) { return (v + 255) & ~(size_t)255; };
  char* ws = (char*)d_ws;
  int*   fine_ptr = (int*)ws;          ws += align((size_t)(NB + 1) * 4);
  int*   cursor   = (int*)ws;          ws += align((size_t)NB * 4);
  int*   hist     = (int*)ws;          ws += align((size_t)NB * 4);
  int2*  ebuf     = (int2*)ws;         ws += align((size_t)E * 8);
  float* s_src    = (float*)ws;        ws += align((size_t)n * HEADS * 4);
  float* s_dst    = (float*)ws;        ws += align((size_t)n * HEADS * 4);
  unsigned int* xb = (unsigned int*)ws; ws += align((size_t)n * 64 * 4);

  hipMemsetAsync(hist, 0, (size_t)NB * 4, stream);

  score_kernel<<<(n + 3) / 4, 256, 0, stream>>>(x, W, a, s_src, s_dst, xb, n);
  hist_kernel<<<(E + 8191) / 8192, 256, 0, stream>>>(src, hist, E, NB);
  scan_kernel<<<1, 256, 0, stream>>>(hist, fine_ptr, cursor, NB, E);
  partition_kernel<<<(E + PT - 1) / PT, 256, 0, stream>>>(src, dst, adj, cursor,
                                                          ebuf, E, NB);
  aggregate_kernel<<<NB, 256, 0, stream>>>(xb, W, s_src, s_dst, fine_ptr,
                                           ebuf, out, n);
}